// Round 7
// baseline (211.371 us; speedup 1.0000x reference)
//
#include <hip/hip_runtime.h>
#include <hip/hip_bf16.h>
#include <math.h>

// Problem constants
#define BB 8
#define NSEQ 1024
#define EMB 768
#define HEADS 8
#define INNER 96
#define HEAD_D 12
#define MLP_DIM 3072
#define ROWS (BB * NSEQ)   // 8192

using short8  = __attribute__((ext_vector_type(8))) short;
using s4b     = __attribute__((ext_vector_type(4))) short;
using floatx4 = __attribute__((ext_vector_type(4))) float;

// global -> LDS async copy, 16 B per lane. LDS dest must be wave-uniform base;
// HW adds lane*16. Global source is per-lane.
#define GLL16(g, l)                                                          \
    __builtin_amdgcn_global_load_lds(                                        \
        (const __attribute__((address_space(1))) void*)(g),                  \
        (__attribute__((address_space(3))) void*)(l), 16, 0, 0)

static __device__ __forceinline__ ushort f2b(float x) {
    __hip_bfloat16 h = __float2bfloat16(x);
    return *reinterpret_cast<ushort*>(&h);
}
static __device__ __forceinline__ uint pk2(float a, float b) {
    return (uint)f2b(a) | ((uint)f2b(b) << 16);
}

// 16x16x16 bf16 MFMA (a,b: 4 bf16 = 2 VGPR; c/d: 4 f32)
static __device__ __forceinline__ floatx4 mfma16(s4b a, s4b b, floatx4 c) {
#if __has_builtin(__builtin_amdgcn_mfma_f32_16x16x16_bf16)
    return __builtin_amdgcn_mfma_f32_16x16x16_bf16(a, b, c, 0, 0, 0);
#elif __has_builtin(__builtin_amdgcn_mfma_f32_16x16x16bf16_1k)
    return __builtin_amdgcn_mfma_f32_16x16x16bf16_1k(a, b, c, 0, 0, 0);
#else
    floatx4 d;
    asm("v_mfma_f32_16x16x16_bf16 %0, %1, %2, %3" : "=v"(d) : "v"(a), "v"(b), "v"(c));
    return d;
#endif
}
#define MFMA32(a, b, c) __builtin_amdgcn_mfma_f32_16x16x32_bf16((a), (b), (c), 0, 0, 0)

// ---------------------------------------------------------------------------
// LayerNorm: one wave per row of 768, bf16 output. 4 rows / 256-thr block.
// ---------------------------------------------------------------------------
__global__ __launch_bounds__(256) void ln_bf16_kernel(const float* __restrict__ x,
                                                      const float* __restrict__ g,
                                                      const float* __restrict__ b,
                                                      ushort* __restrict__ out) {
    int row  = blockIdx.x * 4 + (threadIdx.x >> 6);
    int lane = threadIdx.x & 63;
    const float* xr = x + (size_t)row * EMB;
    float v[12];
    float s = 0.f;
#pragma unroll
    for (int i = 0; i < 12; i++) {
        v[i] = xr[lane + i * 64];
        s += v[i];
    }
#pragma unroll
    for (int off = 32; off; off >>= 1) s += __shfl_xor(s, off);
    float mu = s * (1.0f / EMB);
    float ss = 0.f;
#pragma unroll
    for (int i = 0; i < 12; i++) { float d = v[i] - mu; ss += d * d; }
#pragma unroll
    for (int off = 32; off; off >>= 1) ss += __shfl_xor(ss, off);
    float rstd = rsqrtf(ss * (1.0f / EMB) + 1e-5f);
    ushort* orow = out + (size_t)row * EMB;
#pragma unroll
    for (int i = 0; i < 12; i++) {
        int c = lane + i * 64;
        orow[c] = f2b((v[i] - mu) * rstd * g[c] + b[c]);
    }
}

// ---------------------------------------------------------------------------
// Weight convert+transpose: out[n][k] = bf16(in[k][n]); n in [0,Npad),
// zeros for n >= N. 32x32 tiles via LDS.
// ---------------------------------------------------------------------------
__global__ __launch_bounds__(256) void convt_kernel(const float* __restrict__ in,
                                                    ushort* __restrict__ out,
                                                    int K, int N, int Npad) {
    __shared__ float t[32][33];
    int n0 = blockIdx.x * 32, k0 = blockIdx.y * 32;
    int tx = threadIdx.x, ty = threadIdx.y;
#pragma unroll
    for (int i = 0; i < 32; i += 8) {
        int n = n0 + tx;
        t[ty + i][tx] = (n < N) ? in[(size_t)(k0 + ty + i) * N + n] : 0.f;
    }
    __syncthreads();
#pragma unroll
    for (int i = 0; i < 32; i += 8) {
        out[(size_t)(n0 + ty + i) * K + k0 + tx] = f2b(t[tx][ty + i]);
    }
}

// Variant padding K: out[n][k] for k in [0,Kpad), zero for k >= K.
__global__ __launch_bounds__(256) void convt_pad_kernel(const float* __restrict__ in,
                                                        ushort* __restrict__ out,
                                                        int K, int N, int Kpad) {
    __shared__ float t[32][33];
    int n0 = blockIdx.x * 32, k0 = blockIdx.y * 32;
    int tx = threadIdx.x, ty = threadIdx.y;
#pragma unroll
    for (int i = 0; i < 32; i += 8) {
        int k = k0 + ty + i;
        t[ty + i][tx] = (k < K) ? in[(size_t)k * N + n0 + tx] : 0.f;
    }
    __syncthreads();
#pragma unroll
    for (int i = 0; i < 32; i += 8) {
        out[(size_t)(n0 + ty + i) * Kpad + k0 + tx] = f2b(t[tx][ty + i]);
    }
}

// ---------------------------------------------------------------------------
// Deep-pipelined bf16 MFMA GEMM: C[M,Nn] = A[M,K] @ Bt[Npad,K]^T (+ epilogue)
// Tile 256x128, BK=64, 512 threads = 8 waves (4M x 2N), per-wave 64x64 out.
// TRI-BUFFERED LDS (144 KB): K-tile t lives in buf[t%3].
//   loop t: P1 { vgpr<-ds_read(buf, ks0); stage 3/6 of tile t+2 -> buf[(t+2)%3];
//                bar; lgkmcnt(0); setprio1; 16 MFMA; setprio0; bar }
//           P2 { ds_read ks1; stage 3/6; bar; lgkmcnt(0); 16 MFMA;
//                vmcnt(6) [tile t+1 landed, t+2's 6 stay in flight]; bar }
// Liveness: buf[(t+2)%3] held tile t-1, whose reads completed (lgkmcnt0)
// before t-1/P2's mid-barrier; stages issue after its end-barrier. The tail
// vmcnt+barrier pair gates the NEXT tile's ds_reads across all waves.
// vmcnt never drains to 0 except at the last two boundary steps.
// 1-D grid, bijective XCD-chunked swizzle (T1); gridDim.x % 8 == 0.
// ---------------------------------------------------------------------------
template <int EPI, bool MASKN>
__global__ __launch_bounds__(512) void gemm_mfma8(const ushort* __restrict__ A,
                                                  const ushort* __restrict__ Bt,
                                                  void* __restrict__ Cout,
                                                  const float* __restrict__ bias,
                                                  const float* __restrict__ res,
                                                  int M, int Nn, int K, int gx) {
    __shared__ ushort As3[3][256 * 64];   // 96 KB  [ktile][row][k] swizzled
    __shared__ ushort Bs3[3][128 * 64];   // 48 KB
    int tid = threadIdx.x, lane = tid & 63, w = tid >> 6;
    int wm = w >> 1, wn = w & 1;

    int nwg = gridDim.x, lin = blockIdx.x;
    int swz = (lin & 7) * (nwg >> 3) + (lin >> 3);
    int by = swz / gx, bx = swz - by * gx;
    int m0 = by * 256, n0 = bx * 128;
    int nt = K >> 6;

    // ---- staging geometry: 6 half-tiles of 8 KB; slot s covers rows s*64..+63
    // of A (s<4) or B (s-4). Per thread: 16B chunk (row = base+lane>>3,
    // slot = lane&7); content swizzle: logical k-chunk = slot ^ (row&7).
    int srow = lane >> 3;
    int kchunk = (lane & 7) ^ srow;           // (row&7) == srow for all slots
    const ushort* gA[4];
    const ushort* gB[2];
    uint loAB[4];
#pragma unroll
    for (int s = 0; s < 4; s++) {
        int r = s * 64 + w * 8 + srow;
        gA[s] = A + (size_t)(m0 + r) * K + kchunk * 8;
        loAB[s] = (uint)(s * 512 + w * 64) * 16;
    }
#pragma unroll
    for (int s = 0; s < 2; s++) {
        int r = s * 64 + w * 8 + srow;
        gB[s] = Bt + (size_t)(n0 + r) * K + kchunk * 8;
    }
#define STG_A(s_, buf_, kt_) GLL16(gA[s_] + (kt_) * 64, (char*)&As3[buf_][0] + loAB[s_])
#define STG_B(s_, buf_, kt_) GLL16(gB[s_] + (kt_) * 64, (char*)&Bs3[buf_][0] + loAB[s_])

    // ---- ds_read offsets (ushort units), constant per thread
    int qr = lane & 15, grp = lane >> 4;
    uint aoff[2][4], boff[2][4];
#pragma unroll
    for (int ks = 0; ks < 2; ks++) {
#pragma unroll
        for (int mi = 0; mi < 4; mi++) {
            int r = wm * 64 + mi * 16 + qr;
            aoff[ks][mi] = (uint)(r * 64 + (((ks * 4 + grp) ^ (r & 7)) * 8));
        }
#pragma unroll
        for (int ni = 0; ni < 4; ni++) {
            int c = wn * 64 + ni * 16 + qr;
            boff[ks][ni] = (uint)(c * 64 + (((ks * 4 + grp) ^ (c & 7)) * 8));
        }
    }

    // ---- prologue: stage K-tiles 0,1; own tile-0 landed; barrier -> all landed
    STG_A(0, 0, 0); STG_A(1, 0, 0); STG_A(2, 0, 0); STG_A(3, 0, 0);
    STG_B(0, 0, 0); STG_B(1, 0, 0);
    STG_A(0, 1, 1); STG_A(1, 1, 1); STG_A(2, 1, 1); STG_A(3, 1, 1);
    STG_B(0, 1, 1); STG_B(1, 1, 1);
    asm volatile("s_waitcnt vmcnt(6)" ::: "memory");
    __builtin_amdgcn_sched_barrier(0);
    __builtin_amdgcn_s_barrier();

    floatx4 acc[4][4] = {};

    for (int t = 0; t < nt; ++t) {
        int buf = t % 3;
        int nbuf = buf + 2; if (nbuf >= 3) nbuf -= 3;
        const ushort* Ab = &As3[buf][0];
        const ushort* Bb = &Bs3[buf][0];
        bool st = (t + 2) < nt;
        int t2 = t + 2;

        // ================= Phase 1 (ks = 0) =================
        {
            short8 av0 = *(const short8*)(Ab + aoff[0][0]);
            short8 av1 = *(const short8*)(Ab + aoff[0][1]);
            short8 av2 = *(const short8*)(Ab + aoff[0][2]);
            short8 av3 = *(const short8*)(Ab + aoff[0][3]);
            short8 bv0 = *(const short8*)(Bb + boff[0][0]);
            short8 bv1 = *(const short8*)(Bb + boff[0][1]);
            short8 bv2 = *(const short8*)(Bb + boff[0][2]);
            short8 bv3 = *(const short8*)(Bb + boff[0][3]);
            if (st) { STG_A(0, nbuf, t2); STG_A(1, nbuf, t2); STG_A(2, nbuf, t2); }
            __builtin_amdgcn_s_barrier();
            asm volatile("s_waitcnt lgkmcnt(0)" ::: "memory");
            __builtin_amdgcn_sched_barrier(0);
            __builtin_amdgcn_s_setprio(1);
            acc[0][0] = MFMA32(av0, bv0, acc[0][0]);
            acc[0][1] = MFMA32(av0, bv1, acc[0][1]);
            acc[0][2] = MFMA32(av0, bv2, acc[0][2]);
            acc[0][3] = MFMA32(av0, bv3, acc[0][3]);
            acc[1][0] = MFMA32(av1, bv0, acc[1][0]);
            acc[1][1] = MFMA32(av1, bv1, acc[1][1]);
            acc[1][2] = MFMA32(av1, bv2, acc[1][2]);
            acc[1][3] = MFMA32(av1, bv3, acc[1][3]);
            acc[2][0] = MFMA32(av2, bv0, acc[2][0]);
            acc[2][1] = MFMA32(av2, bv1, acc[2][1]);
            acc[2][2] = MFMA32(av2, bv2, acc[2][2]);
            acc[2][3] = MFMA32(av2, bv3, acc[2][3]);
            acc[3][0] = MFMA32(av3, bv0, acc[3][0]);
            acc[3][1] = MFMA32(av3, bv1, acc[3][1]);
            acc[3][2] = MFMA32(av3, bv2, acc[3][2]);
            acc[3][3] = MFMA32(av3, bv3, acc[3][3]);
            __builtin_amdgcn_s_setprio(0);
            __builtin_amdgcn_sched_barrier(0);
            __builtin_amdgcn_s_barrier();
        }
        // ================= Phase 2 (ks = 1) =================
        {
            short8 av0 = *(const short8*)(Ab + aoff[1][0]);
            short8 av1 = *(const short8*)(Ab + aoff[1][1]);
            short8 av2 = *(const short8*)(Ab + aoff[1][2]);
            short8 av3 = *(const short8*)(Ab + aoff[1][3]);
            short8 bv0 = *(const short8*)(Bb + boff[1][0]);
            short8 bv1 = *(const short8*)(Bb + boff[1][1]);
            short8 bv2 = *(const short8*)(Bb + boff[1][2]);
            short8 bv3 = *(const short8*)(Bb + boff[1][3]);
            if (st) { STG_A(3, nbuf, t2); STG_B(0, nbuf, t2); STG_B(1, nbuf, t2); }
            __builtin_amdgcn_s_barrier();
            asm volatile("s_waitcnt lgkmcnt(0)" ::: "memory");
            __builtin_amdgcn_sched_barrier(0);
            __builtin_amdgcn_s_setprio(1);
            acc[0][0] = MFMA32(av0, bv0, acc[0][0]);
            acc[0][1] = MFMA32(av0, bv1, acc[0][1]);
            acc[0][2] = MFMA32(av0, bv2, acc[0][2]);
            acc[0][3] = MFMA32(av0, bv3, acc[0][3]);
            acc[1][0] = MFMA32(av1, bv0, acc[1][0]);
            acc[1][1] = MFMA32(av1, bv1, acc[1][1]);
            acc[1][2] = MFMA32(av1, bv2, acc[1][2]);
            acc[1][3] = MFMA32(av1, bv3, acc[1][3]);
            acc[2][0] = MFMA32(av2, bv0, acc[2][0]);
            acc[2][1] = MFMA32(av2, bv1, acc[2][1]);
            acc[2][2] = MFMA32(av2, bv2, acc[2][2]);
            acc[2][3] = MFMA32(av2, bv3, acc[2][3]);
            acc[3][0] = MFMA32(av3, bv0, acc[3][0]);
            acc[3][1] = MFMA32(av3, bv1, acc[3][1]);
            acc[3][2] = MFMA32(av3, bv2, acc[3][2]);
            acc[3][3] = MFMA32(av3, bv3, acc[3][3]);
            __builtin_amdgcn_s_setprio(0);
            __builtin_amdgcn_sched_barrier(0);
            // tile-boundary gate: ensure tile t+1 landed for ALL waves before
            // the barrier releases next iteration's ds_reads. Keep this tile's
            // 6 stages in flight (vmcnt(6)); drain only at the tail.
            if (t < nt - 1) {
                if (st) asm volatile("s_waitcnt vmcnt(6)" ::: "memory");
                else    asm volatile("s_waitcnt vmcnt(0)" ::: "memory");
                __builtin_amdgcn_sched_barrier(0);
            }
            __builtin_amdgcn_s_barrier();
        }
    }
#undef STG_A
#undef STG_B

    // ---- epilogue: C/D layout col=lane&15, row=(lane>>4)*4+reg
    int r0 = m0 + wm * 64 + grp * 4;
    int c0 = n0 + wn * 64 + qr;
#pragma unroll
    for (int mi = 0; mi < 4; mi++) {
#pragma unroll
        for (int ni = 0; ni < 4; ni++) {
            int col = c0 + ni * 16;
            if (MASKN && col >= Nn) continue;
#pragma unroll
            for (int r = 0; r < 4; r++) {
                int row = r0 + mi * 16 + r;
                size_t idx = (size_t)row * Nn + col;
                float v = acc[mi][ni][r];
                if constexpr (EPI == 0) {
                    ((float*)Cout)[idx] = v;
                } else if constexpr (EPI == 1) {
                    ((float*)Cout)[idx] = v + bias[col] + res[idx];
                } else {
                    v += bias[col];
                    float u = v * (1.0f + 0.044715f * v * v);
                    float gl = v / (1.0f + __expf(-1.5957691216057308f * u));
                    ((ushort*)Cout)[idx] = f2b(gl);
                }
            }
        }
    }
}

// ---------------------------------------------------------------------------
// MFMA attention. Block = (bh, 128-q group); 512 blocks, 256 thr (4 waves),
// each wave owns 2 q-tiles of 16. K staged bf16 [1024][12], V^T bf16
// [12][1032]. S^T = mfma16(K,Q); P^T C-layout == B-frag layout -> PV direct.
// Output: ao bf16 [8192][128] (cols 96..127 pre-zeroed).
// ---------------------------------------------------------------------------
__global__ __launch_bounds__(256) void attn_mfma_kernel(const float* __restrict__ qkv,
                                                        ushort* __restrict__ ao) {
    __shared__ ushort Kt[NSEQ * 12];     // [j][d]
    __shared__ ushort VT[12 * 1032];     // [d][j], stride 1032
    int bh = blockIdx.x >> 3, qg = blockIdx.x & 7;
    int b = bh >> 3, h = bh & 7;
    int tid = threadIdx.x;
    const float* base = qkv + (size_t)b * NSEQ * (3 * INNER);

#pragma unroll
    for (int i = 0; i < 4; i++) {
        int j = i * 256 + tid;
        const float* kp = base + (size_t)j * (3 * INNER) + INNER + h * HEAD_D;
        float4 a0 = *(const float4*)(kp);
        float4 a1 = *(const float4*)(kp + 4);
        float4 a2 = *(const float4*)(kp + 8);
        uint2* kw = (uint2*)(&Kt[j * 12]);
        kw[0] = make_uint2(pk2(a0.x, a0.y), pk2(a0.z, a0.w));
        kw[1] = make_uint2(pk2(a1.x, a1.y), pk2(a1.z, a1.w));
        kw[2] = make_uint2(pk2(a2.x, a2.y), pk2(a2.z, a2.w));
        const float* vp = kp + INNER;
        float4 v0 = *(const float4*)(vp);
        float4 v1 = *(const float4*)(vp + 4);
        float4 v2 = *(const float4*)(vp + 8);
        VT[0 * 1032 + j] = f2b(v0.x);  VT[1 * 1032 + j]  = f2b(v0.y);
        VT[2 * 1032 + j] = f2b(v0.z);  VT[3 * 1032 + j]  = f2b(v0.w);
        VT[4 * 1032 + j] = f2b(v1.x);  VT[5 * 1032 + j]  = f2b(v1.y);
        VT[6 * 1032 + j] = f2b(v1.z);  VT[7 * 1032 + j]  = f2b(v1.w);
        VT[8 * 1032 + j] = f2b(v2.x);  VT[9 * 1032 + j]  = f2b(v2.y);
        VT[10 * 1032 + j] = f2b(v2.z); VT[11 * 1032 + j] = f2b(v2.w);
    }
    __syncthreads();

    int lane = tid & 63, wave = tid >> 6;
    int qrow = lane & 15, grp = lane >> 4;
    const float scale = 0.102062072615966f;  // 96^-0.5

    s4b qf[2];
#pragma unroll
    for (int t = 0; t < 2; t++) {
        qf[t] = (s4b)0;
        if (grp < 3) {
            int q = qg * 128 + (wave * 2 + t) * 16 + qrow;
            const float* qp = base + (size_t)q * (3 * INNER) + h * HEAD_D + grp * 4;
            float4 qv = *(const float4*)(qp);
            uint2 u = make_uint2(pk2(qv.x * scale, qv.y * scale),
                                 pk2(qv.z * scale, qv.w * scale));
            qf[t] = __builtin_bit_cast(s4b, u);
        }
    }

    floatx4 acc[2] = {};
    float l[2] = {0.f, 0.f};
    int kc = (grp < 3) ? grp : 0;
    int dv = (qrow < 12) ? qrow : 0;
    bool kz = (grp == 3), vz = (qrow >= 12);
    const floatx4 z4 = {};

    for (int jt = 0; jt < 64; jt++) {
        s4b kf = *(const s4b*)(&Kt[(jt * 16 + qrow) * 12 + kc * 4]);
        if (kz) kf = (s4b)0;
        s4b vf = *(const s4b*)(&VT[dv * 1032 + jt * 16 + grp * 4]);
        if (vz) vf = (s4b)0;
#pragma unroll
        for (int t = 0; t < 2; t++) {
            floatx4 st = mfma16(kf, qf[t], z4);
            float p0 = __expf(st[0]), p1 = __expf(st[1]);
            float p2 = __expf(st[2]), p3 = __expf(st[3]);
            l[t] += (p0 + p1) + (p2 + p3);
            uint2 u = make_uint2(pk2(p0, p1), pk2(p2, p3));
            acc[t] = mfma16(vf, __builtin_bit_cast(s4b, u), acc[t]);
        }
    }

#pragma unroll
    for (int t = 0; t < 2; t++) {
        float lt = l[t];
        lt += __shfl_xor(lt, 16);
        lt += __shfl_xor(lt, 32);
        float inv = 1.f / lt;
        if (grp < 3) {
            int q = qg * 128 + (wave * 2 + t) * 16 + qrow;
            ushort4 o;
            o.x = f2b(acc[t][0] * inv);
            o.y = f2b(acc[t][1] * inv);
            o.z = f2b(acc[t][2] * inv);
            o.w = f2b(acc[t][3] * inv);
            *reinterpret_cast<ushort4*>(&ao[(size_t)(b * NSEQ + q) * 128 + h * HEAD_D + grp * 4]) = o;
        }
    }
}

// ---------------------------------------------------------------------------
// Launch
// ---------------------------------------------------------------------------
extern "C" void kernel_launch(void* const* d_in, const int* in_sizes, int n_in,
                              void* d_out, int out_size, void* d_ws, size_t ws_size,
                              hipStream_t stream) {
    const float* inputs = (const float*)d_in[0];
    const float* ln1_g  = (const float*)d_in[3];
    const float* ln1_b  = (const float*)d_in[4];
    const float* w_qkv  = (const float*)d_in[5];
    const float* w_proj = (const float*)d_in[6];
    const float* b_proj = (const float*)d_in[7];
    const float* ln2_g  = (const float*)d_in[8];
    const float* ln2_b  = (const float*)d_in[9];
    const float* w1     = (const float*)d_in[10];
    const float* b1     = (const float*)d_in[11];
    const float* w2     = (const float*)d_in[12];
    const float* b2     = (const float*)d_in[13];
    float* out = (float*)d_out;

    // Workspace layout (bytes):
    //  h_bf    : 8192*768*2   = 12,582,912  @ 0
    //  qkv     : 8192*288*4   =  9,437,184  @ 12,582,912
    //  ao_pad  : 8192*128*2   =  2,097,152  @ 22,020,096  (bf16, K-padded)
    //  wproj_t : 768*128*2    =    196,608  @ 24,117,248
    //  x1      : 8192*768*4   = 25,165,824  @ 25,165,824
    //  m2      : 8192*3072*2  = 50,331,648  @ 50,331,648
    //  wqkv_t  : 384*768*2    =    589,824  @ 100,663,296
    //  w1_t    : 3072*768*2   =  4,718,592  @ 101,253,120
    //  w2_t    : 768*3072*2   =  4,718,592  @ 105,971,712
    char* ws = (char*)d_ws;
    ushort* h_bf    = (ushort*)(ws);
    float*  qkv     = (float*)(ws + 12582912);
    ushort* ao_pad  = (ushort*)(ws + 22020096);
    ushort* wproj_t = (ushort*)(ws + 24117248);
    float*  x1      = (float*)(ws + 25165824);
    ushort* m2      = (ushort*)(ws + 50331648);
    ushort* wqkv_t  = (ushort*)(ws + 100663296);
    ushort* w1_t    = (ushort*)(ws + 101253120);
    ushort* w2_t    = (ushort*)(ws + 105971712);

    dim3 tb(32, 8);
    convt_kernel<<<dim3(12, 24), tb, 0, stream>>>(w_qkv, wqkv_t, EMB, 3 * INNER, 384);
    convt_kernel<<<dim3(96, 24), tb, 0, stream>>>(w1, w1_t, EMB, MLP_DIM, MLP_DIM);
    convt_kernel<<<dim3(24, 96), tb, 0, stream>>>(w2, w2_t, MLP_DIM, EMB, EMB);
    convt_pad_kernel<<<dim3(24, 4), tb, 0, stream>>>(w_proj, wproj_t, INNER, EMB, 128);

    // 1) LN1 -> bf16
    ln_bf16_kernel<<<ROWS / 4, 256, 0, stream>>>(inputs, ln1_g, ln1_b, h_bf);
    // 2) qkv = h @ w_qkv   [8192,288] K=768 (Npad=384); grid 32x3 = 96
    gemm_mfma8<0, true><<<96, 512, 0, stream>>>(
        h_bf, wqkv_t, qkv, nullptr, nullptr, ROWS, 3 * INNER, EMB, 3);
    // 3) attention -> ao_pad bf16 [8192,128]
    hipMemsetAsync(ao_pad, 0, (size_t)ROWS * 128 * 2, stream);
    attn_mfma_kernel<<<512, 256, 0, stream>>>(qkv, ao_pad);
    // 4) x1 = inputs + ao @ w_proj + b_proj   [8192,768] K=128(pad); grid 32x6
    gemm_mfma8<1, false><<<192, 512, 0, stream>>>(
        ao_pad, wproj_t, x1, b_proj, inputs, ROWS, EMB, 128, 6);
    // 5) LN2 -> bf16
    ln_bf16_kernel<<<ROWS / 4, 256, 0, stream>>>(x1, ln2_g, ln2_b, h_bf);
    // 6) m2 = gelu(h @ w1 + b1) -> bf16   [8192,3072] K=768; grid 32x24 = 768
    gemm_mfma8<2, false><<<768, 512, 0, stream>>>(
        h_bf, w1_t, m2, b1, nullptr, ROWS, MLP_DIM, EMB, 24);
    // 7) out = x1 + m2 @ w2 + b2   [8192,768] K=3072; grid 32x6 = 192
    gemm_mfma8<1, false><<<192, 512, 0, stream>>>(
        m2, w2_t, out, b2, x1, ROWS, EMB, MLP_DIM, 6);
}

// Round 8
// 199.738 us; speedup vs baseline: 1.0582x; 1.0582x over previous
//
#include <hip/hip_runtime.h>
#include <hip/hip_bf16.h>
#include <math.h>

// Problem constants
#define BB 8
#define NSEQ 1024
#define EMB 768
#define HEADS 8
#define INNER 96
#define HEAD_D 12
#define MLP_DIM 3072
#define ROWS (BB * NSEQ)   // 8192

using short8  = __attribute__((ext_vector_type(8))) short;
using s4b     = __attribute__((ext_vector_type(4))) short;
using floatx4 = __attribute__((ext_vector_type(4))) float;

// global -> LDS async copy, 16 B per lane. LDS dest must be wave-uniform base;
// HW adds lane*16. Global source is per-lane.
#define GLL16(g, l)                                                          \
    __builtin_amdgcn_global_load_lds(                                        \
        (const __attribute__((address_space(1))) void*)(g),                  \
        (__attribute__((address_space(3))) void*)(l), 16, 0, 0)

static __device__ __forceinline__ ushort f2b(float x) {
    __hip_bfloat16 h = __float2bfloat16(x);
    return *reinterpret_cast<ushort*>(&h);
}
static __device__ __forceinline__ uint pk2(float a, float b) {
    return (uint)f2b(a) | ((uint)f2b(b) << 16);
}

// 16x16x16 bf16 MFMA (a,b: 4 bf16 = 2 VGPR; c/d: 4 f32)
static __device__ __forceinline__ floatx4 mfma16(s4b a, s4b b, floatx4 c) {
#if __has_builtin(__builtin_amdgcn_mfma_f32_16x16x16_bf16)
    return __builtin_amdgcn_mfma_f32_16x16x16_bf16(a, b, c, 0, 0, 0);
#elif __has_builtin(__builtin_amdgcn_mfma_f32_16x16x16bf16_1k)
    return __builtin_amdgcn_mfma_f32_16x16x16bf16_1k(a, b, c, 0, 0, 0);
#else
    floatx4 d;
    asm("v_mfma_f32_16x16x16_bf16 %0, %1, %2, %3" : "=v"(d) : "v"(a), "v"(b), "v"(c));
    return d;
#endif
}
#define MFMA32(a, b, c) __builtin_amdgcn_mfma_f32_16x16x32_bf16((a), (b), (c), 0, 0, 0)

// ---------------------------------------------------------------------------
// LayerNorm: one wave per row of 768, bf16 output. 4 rows / 256-thr block.
// ---------------------------------------------------------------------------
__global__ __launch_bounds__(256) void ln_bf16_kernel(const float* __restrict__ x,
                                                      const float* __restrict__ g,
                                                      const float* __restrict__ b,
                                                      ushort* __restrict__ out) {
    int row  = blockIdx.x * 4 + (threadIdx.x >> 6);
    int lane = threadIdx.x & 63;
    const float* xr = x + (size_t)row * EMB;
    float v[12];
    float s = 0.f;
#pragma unroll
    for (int i = 0; i < 12; i++) {
        v[i] = xr[lane + i * 64];
        s += v[i];
    }
#pragma unroll
    for (int off = 32; off; off >>= 1) s += __shfl_xor(s, off);
    float mu = s * (1.0f / EMB);
    float ss = 0.f;
#pragma unroll
    for (int i = 0; i < 12; i++) { float d = v[i] - mu; ss += d * d; }
#pragma unroll
    for (int off = 32; off; off >>= 1) ss += __shfl_xor(ss, off);
    float rstd = rsqrtf(ss * (1.0f / EMB) + 1e-5f);
    ushort* orow = out + (size_t)row * EMB;
#pragma unroll
    for (int i = 0; i < 12; i++) {
        int c = lane + i * 64;
        orow[c] = f2b((v[i] - mu) * rstd * g[c] + b[c]);
    }
}

// ---------------------------------------------------------------------------
// Weight convert+transpose: out[n][k] = bf16(in[k][n]); n in [0,Npad),
// zeros for n >= N. 32x32 tiles via LDS.
// ---------------------------------------------------------------------------
__global__ __launch_bounds__(256) void convt_kernel(const float* __restrict__ in,
                                                    ushort* __restrict__ out,
                                                    int K, int N, int Npad) {
    __shared__ float t[32][33];
    int n0 = blockIdx.x * 32, k0 = blockIdx.y * 32;
    int tx = threadIdx.x, ty = threadIdx.y;
#pragma unroll
    for (int i = 0; i < 32; i += 8) {
        int n = n0 + tx;
        t[ty + i][tx] = (n < N) ? in[(size_t)(k0 + ty + i) * N + n] : 0.f;
    }
    __syncthreads();
#pragma unroll
    for (int i = 0; i < 32; i += 8) {
        out[(size_t)(n0 + ty + i) * K + k0 + tx] = f2b(t[tx][ty + i]);
    }
}

// Variant padding K: out[n][k] for k in [0,Kpad), zero for k >= K.
__global__ __launch_bounds__(256) void convt_pad_kernel(const float* __restrict__ in,
                                                        ushort* __restrict__ out,
                                                        int K, int N, int Kpad) {
    __shared__ float t[32][33];
    int n0 = blockIdx.x * 32, k0 = blockIdx.y * 32;
    int tx = threadIdx.x, ty = threadIdx.y;
#pragma unroll
    for (int i = 0; i < 32; i += 8) {
        int k = k0 + ty + i;
        t[ty + i][tx] = (k < K) ? in[(size_t)k * N + n0 + tx] : 0.f;
    }
    __syncthreads();
#pragma unroll
    for (int i = 0; i < 32; i += 8) {
        out[(size_t)(n0 + ty + i) * Kpad + k0 + tx] = f2b(t[tx][ty + i]);
    }
}

// ---------------------------------------------------------------------------
// bf16 MFMA GEMM: C[M,Nn] = A[M,K](bf16) @ Bt[Npad,K](bf16)^T  (+ epilogue)
// 128x128 tile, BK=64, 4 waves (2x2), 4x4 16x16x32 fragments per wave.
// Double-buffered LDS (64 KB -> 2 blocks/CU) + counted-vmcnt pipeline with
// split-lgkm schedule:
//   iter t: ds_read ks0(8), ks1(8); lgkmcnt(8); [MFMA ks0 x16]   <- hides ks1
//           lgkmcnt(0); barrier;               <- buf[cur] dead for all waves
//           STAGE(t+2 -> cur);  [MFMA ks1 x16] <- hides stage issue
//           vmcnt(8) [t+1 landed, t+2 in flight]; barrier
// Loads never drain to 0 in-loop. setprio(1) around MFMA clusters (T5).
// 1-D grid, bijective XCD-chunked swizzle (T1); gridDim.x % 8 == 0.
// ---------------------------------------------------------------------------
template <int EPI, bool MASKN>
__global__ __launch_bounds__(256) void gemm_mfma(const ushort* __restrict__ A,
                                                 const ushort* __restrict__ Bt,
                                                 void* __restrict__ Cout,
                                                 const float* __restrict__ bias,
                                                 const float* __restrict__ res,
                                                 int M, int Nn, int K, int gx) {
    __shared__ ushort As[2][128 * 64];  // [row][k] swizzled: chunk c at slot c^(row&7)
    __shared__ ushort Bs[2][128 * 64];
    int tid  = threadIdx.x;
    int lane = tid & 63, wave = tid >> 6;
    int wm = wave >> 1, wn = wave & 1;

    // XCD-chunked bijective swizzle: HW assigns block i -> XCD i%8.
    int nwg = gridDim.x;
    int lin = blockIdx.x;
    int swz = (lin & 7) * (nwg >> 3) + (lin >> 3);
    int by = swz / gx, bx = swz - by * gx;
    int m0 = by * 128, n0 = bx * 128;

    floatx4 acc[4][4] = {};

    int srow = lane >> 3;
    int slot = lane & 7;
    int nt = K >> 6;

    // stage one 64-k tile (A half + B half) into buffer bufi: 8 GLL16/thread
    auto STAGE = [&](int t, int bufi) {
        int k0 = t << 6;
#pragma unroll
        for (int r = 0; r < 4; r++) {
            int row = r * 32 + wave * 8 + srow;
            int c   = slot ^ (row & 7);
            const ushort* ga = A  + (size_t)(m0 + row) * K + k0 + c * 8;
            const ushort* gb = Bt + (size_t)(n0 + row) * K + k0 + c * 8;
            GLL16(ga, (char*)&As[bufi][0] + r * 4096 + wave * 1024);
            GLL16(gb, (char*)&Bs[bufi][0] + r * 4096 + wave * 1024);
        }
    };

    // ds_read offsets (ushort units), constant per thread
    int qr = lane & 15, grp = lane >> 4;
    uint aoff[2][4], boff[2][4];
#pragma unroll
    for (int ks = 0; ks < 2; ks++) {
#pragma unroll
        for (int mi = 0; mi < 4; mi++) {
            int r = wm * 64 + mi * 16 + qr;
            aoff[ks][mi] = (uint)(r * 64 + (((ks * 4 + grp) ^ (r & 7)) * 8));
        }
#pragma unroll
        for (int ni = 0; ni < 4; ni++) {
            int c = wn * 64 + ni * 16 + qr;
            boff[ks][ni] = (uint)(c * 64 + (((ks * 4 + grp) ^ (c & 7)) * 8));
        }
    }

    // Prologue: fill both buffers, wait for tile 0 only (counted).
    STAGE(0, 0);
    STAGE(1, 1);
    asm volatile("s_waitcnt vmcnt(8)" ::: "memory");
    __builtin_amdgcn_sched_barrier(0);
    __builtin_amdgcn_s_barrier();

    int cur = 0;
    for (int t = 0; t < nt; ++t) {
        const ushort* Ab = &As[cur][0];
        const ushort* Bb = &Bs[cur][0];
        // 1. issue ks0 reads, then ks1 reads
        short8 a0[4], b0[4], a1[4], b1[4];
#pragma unroll
        for (int mi = 0; mi < 4; mi++) a0[mi] = *(const short8*)(Ab + aoff[0][mi]);
#pragma unroll
        for (int ni = 0; ni < 4; ni++) b0[ni] = *(const short8*)(Bb + boff[0][ni]);
#pragma unroll
        for (int mi = 0; mi < 4; mi++) a1[mi] = *(const short8*)(Ab + aoff[1][mi]);
#pragma unroll
        for (int ni = 0; ni < 4; ni++) b1[ni] = *(const short8*)(Bb + boff[1][ni]);

        // 2. ks0 ready -> MFMA ks0 while ks1 reads return (register-only, pre-barrier)
        asm volatile("s_waitcnt lgkmcnt(8)" ::: "memory");
        __builtin_amdgcn_sched_barrier(0);
        __builtin_amdgcn_s_setprio(1);
#pragma unroll
        for (int mi = 0; mi < 4; mi++)
#pragma unroll
            for (int ni = 0; ni < 4; ni++)
                acc[mi][ni] = MFMA32(a0[mi], b0[ni], acc[mi][ni]);
        __builtin_amdgcn_s_setprio(0);

        // 3. all reads done -> barrier -> buf[cur] dead for all waves
        asm volatile("s_waitcnt lgkmcnt(0)" ::: "memory");
        __builtin_amdgcn_sched_barrier(0);
        __builtin_amdgcn_s_barrier();

        // 4. stage tile t+2 into the dead buffer (clamped; tail re-load benign)
        int tn = t + 2; if (tn > nt - 1) tn = nt - 1;
        STAGE(tn, cur);

        // 5. MFMA ks1 (hides stage issue + vmem latency)
        __builtin_amdgcn_s_setprio(1);
#pragma unroll
        for (int mi = 0; mi < 4; mi++)
#pragma unroll
            for (int ni = 0; ni < 4; ni++)
                acc[mi][ni] = MFMA32(a1[mi], b1[ni], acc[mi][ni]);
        __builtin_amdgcn_s_setprio(0);

        // 6. counted gate: tile t+1's 8 loads landed; t+2's stay in flight
        asm volatile("s_waitcnt vmcnt(8)" ::: "memory");
        __builtin_amdgcn_sched_barrier(0);
        __builtin_amdgcn_s_barrier();
        cur ^= 1;
    }

    int r0 = m0 + wm * 64 + grp * 4;
    int c0 = n0 + wn * 64 + qr;
#pragma unroll
    for (int mi = 0; mi < 4; mi++) {
#pragma unroll
        for (int ni = 0; ni < 4; ni++) {
            int col = c0 + ni * 16;
            if (MASKN && col >= Nn) continue;
#pragma unroll
            for (int r = 0; r < 4; r++) {
                int row = r0 + mi * 16 + r;
                size_t idx = (size_t)row * Nn + col;
                float v = acc[mi][ni][r];
                if constexpr (EPI == 0) {
                    ((float*)Cout)[idx] = v;
                } else if constexpr (EPI == 1) {
                    ((float*)Cout)[idx] = v + bias[col] + res[idx];
                } else {
                    v += bias[col];
                    // tanh-GELU via sigmoid; |err| ~3e-4 << bf16 rounding of m2.
                    float u = v * (1.0f + 0.044715f * v * v);
                    float gl = v / (1.0f + __expf(-1.5957691216057308f * u));
                    ((ushort*)Cout)[idx] = f2b(gl);
                }
            }
        }
    }
}

// ---------------------------------------------------------------------------
// MFMA attention. Block = (bh, 128-q group); 512 blocks, 256 thr (4 waves),
// each wave owns 2 q-tiles of 16. K staged bf16 [1024][12], V^T bf16
// [12][1032]. S^T = mfma16(K,Q); P^T C-layout == B-frag layout -> PV direct.
// Output: ao bf16 [8192][128] (cols 96..127 pre-zeroed).
// ---------------------------------------------------------------------------
__global__ __launch_bounds__(256) void attn_mfma_kernel(const float* __restrict__ qkv,
                                                        ushort* __restrict__ ao) {
    __shared__ ushort Kt[NSEQ * 12];     // [j][d]
    __shared__ ushort VT[12 * 1032];     // [d][j], stride 1032
    int bh = blockIdx.x >> 3, qg = blockIdx.x & 7;
    int b = bh >> 3, h = bh & 7;
    int tid = threadIdx.x;
    const float* base = qkv + (size_t)b * NSEQ * (3 * INNER);

#pragma unroll
    for (int i = 0; i < 4; i++) {
        int j = i * 256 + tid;
        const float* kp = base + (size_t)j * (3 * INNER) + INNER + h * HEAD_D;
        float4 a0 = *(const float4*)(kp);
        float4 a1 = *(const float4*)(kp + 4);
        float4 a2 = *(const float4*)(kp + 8);
        uint2* kw = (uint2*)(&Kt[j * 12]);
        kw[0] = make_uint2(pk2(a0.x, a0.y), pk2(a0.z, a0.w));
        kw[1] = make_uint2(pk2(a1.x, a1.y), pk2(a1.z, a1.w));
        kw[2] = make_uint2(pk2(a2.x, a2.y), pk2(a2.z, a2.w));
        const float* vp = kp + INNER;
        float4 v0 = *(const float4*)(vp);
        float4 v1 = *(const float4*)(vp + 4);
        float4 v2 = *(const float4*)(vp + 8);
        VT[0 * 1032 + j] = f2b(v0.x);  VT[1 * 1032 + j]  = f2b(v0.y);
        VT[2 * 1032 + j] = f2b(v0.z);  VT[3 * 1032 + j]  = f2b(v0.w);
        VT[4 * 1032 + j] = f2b(v1.x);  VT[5 * 1032 + j]  = f2b(v1.y);
        VT[6 * 1032 + j] = f2b(v1.z);  VT[7 * 1032 + j]  = f2b(v1.w);
        VT[8 * 1032 + j] = f2b(v2.x);  VT[9 * 1032 + j]  = f2b(v2.y);
        VT[10 * 1032 + j] = f2b(v2.z); VT[11 * 1032 + j] = f2b(v2.w);
    }
    __syncthreads();

    int lane = tid & 63, wave = tid >> 6;
    int qrow = lane & 15, grp = lane >> 4;
    const float scale = 0.102062072615966f;  // 96^-0.5

    s4b qf[2];
#pragma unroll
    for (int t = 0; t < 2; t++) {
        qf[t] = (s4b)0;
        if (grp < 3) {
            int q = qg * 128 + (wave * 2 + t) * 16 + qrow;
            const float* qp = base + (size_t)q * (3 * INNER) + h * HEAD_D + grp * 4;
            float4 qv = *(const float4*)(qp);
            uint2 u = make_uint2(pk2(qv.x * scale, qv.y * scale),
                                 pk2(qv.z * scale, qv.w * scale));
            qf[t] = __builtin_bit_cast(s4b, u);
        }
    }

    floatx4 acc[2] = {};
    float l[2] = {0.f, 0.f};
    int kc = (grp < 3) ? grp : 0;
    int dv = (qrow < 12) ? qrow : 0;
    bool kz = (grp == 3), vz = (qrow >= 12);
    const floatx4 z4 = {};

    for (int jt = 0; jt < 64; jt++) {
        s4b kf = *(const s4b*)(&Kt[(jt * 16 + qrow) * 12 + kc * 4]);
        if (kz) kf = (s4b)0;
        s4b vf = *(const s4b*)(&VT[dv * 1032 + jt * 16 + grp * 4]);
        if (vz) vf = (s4b)0;
#pragma unroll
        for (int t = 0; t < 2; t++) {
            floatx4 st = mfma16(kf, qf[t], z4);
            float p0 = __expf(st[0]), p1 = __expf(st[1]);
            float p2 = __expf(st[2]), p3 = __expf(st[3]);
            l[t] += (p0 + p1) + (p2 + p3);
            uint2 u = make_uint2(pk2(p0, p1), pk2(p2, p3));
            acc[t] = mfma16(vf, __builtin_bit_cast(s4b, u), acc[t]);
        }
    }

#pragma unroll
    for (int t = 0; t < 2; t++) {
        float lt = l[t];
        lt += __shfl_xor(lt, 16);
        lt += __shfl_xor(lt, 32);
        float inv = 1.f / lt;
        if (grp < 3) {
            int q = qg * 128 + (wave * 2 + t) * 16 + qrow;
            ushort4 o;
            o.x = f2b(acc[t][0] * inv);
            o.y = f2b(acc[t][1] * inv);
            o.z = f2b(acc[t][2] * inv);
            o.w = f2b(acc[t][3] * inv);
            *reinterpret_cast<ushort4*>(&ao[(size_t)(b * NSEQ + q) * 128 + h * HEAD_D + grp * 4]) = o;
        }
    }
}

// ---------------------------------------------------------------------------
// Launch
// ---------------------------------------------------------------------------
extern "C" void kernel_launch(void* const* d_in, const int* in_sizes, int n_in,
                              void* d_out, int out_size, void* d_ws, size_t ws_size,
                              hipStream_t stream) {
    const float* inputs = (const float*)d_in[0];
    const float* ln1_g  = (const float*)d_in[3];
    const float* ln1_b  = (const float*)d_in[4];
    const float* w_qkv  = (const float*)d_in[5];
    const float* w_proj = (const float*)d_in[6];
    const float* b_proj = (const float*)d_in[7];
    const float* ln2_g  = (const float*)d_in[8];
    const float* ln2_b  = (const float*)d_in[9];
    const float* w1     = (const float*)d_in[10];
    const float* b1     = (const float*)d_in[11];
    const float* w2     = (const float*)d_in[12];
    const float* b2     = (const float*)d_in[13];
    float* out = (float*)d_out;

    // Workspace layout (bytes):
    //  h_bf    : 8192*768*2   = 12,582,912  @ 0
    //  qkv     : 8192*288*4   =  9,437,184  @ 12,582,912
    //  ao_pad  : 8192*128*2   =  2,097,152  @ 22,020,096  (bf16, K-padded)
    //  wproj_t : 768*128*2    =    196,608  @ 24,117,248
    //  x1      : 8192*768*4   = 25,165,824  @ 25,165,824
    //  m2      : 8192*3072*2  = 50,331,648  @ 50,331,648
    //  wqkv_t  : 384*768*2    =    589,824  @ 100,663,296
    //  w1_t    : 3072*768*2   =  4,718,592  @ 101,253,120
    //  w2_t    : 768*3072*2   =  4,718,592  @ 105,971,712
    char* ws = (char*)d_ws;
    ushort* h_bf    = (ushort*)(ws);
    float*  qkv     = (float*)(ws + 12582912);
    ushort* ao_pad  = (ushort*)(ws + 22020096);
    ushort* wproj_t = (ushort*)(ws + 24117248);
    float*  x1      = (float*)(ws + 25165824);
    ushort* m2      = (ushort*)(ws + 50331648);
    ushort* wqkv_t  = (ushort*)(ws + 100663296);
    ushort* w1_t    = (ushort*)(ws + 101253120);
    ushort* w2_t    = (ushort*)(ws + 105971712);

    dim3 tb(32, 8);
    convt_kernel<<<dim3(12, 24), tb, 0, stream>>>(w_qkv, wqkv_t, EMB, 3 * INNER, 384);
    convt_kernel<<<dim3(96, 24), tb, 0, stream>>>(w1, w1_t, EMB, MLP_DIM, MLP_DIM);
    convt_kernel<<<dim3(24, 96), tb, 0, stream>>>(w2, w2_t, MLP_DIM, EMB, EMB);
    convt_pad_kernel<<<dim3(24, 4), tb, 0, stream>>>(w_proj, wproj_t, INNER, EMB, 128);

    // 1) LN1 -> bf16
    ln_bf16_kernel<<<ROWS / 4, 256, 0, stream>>>(inputs, ln1_g, ln1_b, h_bf);
    // 2) qkv = h @ w_qkv   [8192,288] K=768 (Npad=384); grid 3x64=192 (%8==0)
    gemm_mfma<0, true><<<3 * (ROWS / 128), 256, 0, stream>>>(
        h_bf, wqkv_t, qkv, nullptr, nullptr, ROWS, 3 * INNER, EMB, 3);
    // 3) attention -> ao_pad bf16 [8192,128]
    hipMemsetAsync(ao_pad, 0, (size_t)ROWS * 128 * 2, stream);
    attn_mfma_kernel<<<512, 256, 0, stream>>>(qkv, ao_pad);
    // 4) x1 = inputs + ao @ w_proj + b_proj   [8192,768] K=128(pad); grid 6x64
    gemm_mfma<1, false><<<6 * (ROWS / 128), 256, 0, stream>>>(
        ao_pad, wproj_t, x1, b_proj, inputs, ROWS, EMB, 128, 6);
    // 5) LN2 -> bf16
    ln_bf16_kernel<<<ROWS / 4, 256, 0, stream>>>(x1, ln2_g, ln2_b, h_bf);
    // 6) m2 = gelu(h @ w1 + b1) -> bf16   [8192,3072] K=768; grid 24x64=1536
    gemm_mfma<2, false><<<24 * (ROWS / 128), 256, 0, stream>>>(
        h_bf, w1_t, m2, b1, nullptr, ROWS, MLP_DIM, EMB, 24);
    // 7) out = x1 + m2 @ w2 + b2   [8192,768] K=3072; grid 6x64=384
    gemm_mfma<1, false><<<6 * (ROWS / 128), 256, 0, stream>>>(
        m2, w2_t, out, b2, x1, ROWS, EMB, MLP_DIM, 6);
}